// Round 3
// baseline (895.793 us; speedup 1.0000x reference)
//
#include <hip/hip_runtime.h>

#define NN 20000
#define NE 640000
#define ECH 80000    // edge chunk; wbuf reused per chunk (8 chunks)

__device__ __forceinline__ float silu_f(float x) {
    return x / (1.0f + __expf(-x));
}

// ---------------------------------------------------------------------------
// Kernel A1: per-node y precompute (y0/y1/y2 only).
// block = 256 = 8 nodes x 32 channels
// ---------------------------------------------------------------------------
__global__ __launch_bounds__(256) void node_y(
    const float* __restrict__ x,
    const float* __restrict__ W10,
    const float* __restrict__ W11,
    const float* __restrict__ W12,
    float* __restrict__ yAll)
{
    __shared__ float xs[8][288];
    __shared__ float w10[1024];
    __shared__ float w11[1024];
    __shared__ float w12[1024];
    const int tid = threadIdx.x;
    const int nodeBase = blockIdx.x * 8;

    for (int i = tid; i < 1024; i += 256) { w10[i] = W10[i]; w11[i] = W11[i]; w12[i] = W12[i]; }
    for (int i = tid; i < 8 * 288; i += 256) {
        int nl = i / 288, c = i % 288;
        int n = nodeBase + nl;
        xs[nl][c] = (n < NN) ? x[(long)n * 288 + c] : 0.f;
    }
    __syncthreads();

    const int nl = tid >> 5, v = tid & 31;
    const int n = nodeBase + nl;
    if (n >= NN) return;

    const float inv_mul = 0.17677669529663687f;  // 1/sqrt(32)
    float* yrow = yAll + (long)n * 288;

    {
        float a = 0.f;
        #pragma unroll
        for (int u = 0; u < 32; ++u) a += xs[nl][u] * w10[u * 32 + v];
        yrow[v] = a * inv_mul;
    }
    {
        float a0 = 0.f, a1 = 0.f, a2 = 0.f;
        #pragma unroll
        for (int u = 0; u < 32; ++u) {
            float wv = w11[u * 32 + v];
            a0 += xs[nl][32 + u * 3 + 0] * wv;
            a1 += xs[nl][32 + u * 3 + 1] * wv;
            a2 += xs[nl][32 + u * 3 + 2] * wv;
        }
        yrow[32 + v * 3 + 0] = a0 * inv_mul;
        yrow[32 + v * 3 + 1] = a1 * inv_mul;
        yrow[32 + v * 3 + 2] = a2 * inv_mul;
    }
    {
        float a[5] = {0.f, 0.f, 0.f, 0.f, 0.f};
        #pragma unroll
        for (int u = 0; u < 32; ++u) {
            float wv = w12[u * 32 + v];
            #pragma unroll
            for (int m = 0; m < 5; ++m) a[m] += xs[nl][128 + u * 5 + m] * wv;
        }
        #pragma unroll
        for (int m = 0; m < 5; ++m) yrow[128 + v * 5 + m] = a[m] * inv_mul;
    }
}

// ---------------------------------------------------------------------------
// Kernel A2: sc as a small GEMM. sc[h,n,w] = sum_{u,t} x0[n,u] na[n,t]
// scW[h,u,t,w] / sqrt(128). B = scW reshaped [128 x 96] in LDS (conflict-free
// lane-consecutive reads); A built on the fly from x0s (broadcast) x na
// (registers). Tile = 64 nodes/block; thread = (group g, col c): 8 nodes x
// 3 cols {c, c+32, c+64}.
// ---------------------------------------------------------------------------
__global__ __launch_bounds__(256) void node_sc(
    const float* __restrict__ x,
    const float* __restrict__ na,
    const float* __restrict__ scW,
    float* __restrict__ sc)
{
    __shared__ float B[128 * 96];      // [(u*4+t)*96 + h*32+w]
    __shared__ float x0s[64 * 32];
    __shared__ float nas[64 * 4];
    const int tid = threadIdx.x;
    const int nodeBase = blockIdx.x * 64;

    for (int i = tid; i < 12288; i += 256) {
        int h = i >> 12, r = i & 4095;
        int u = r >> 7, r2 = r & 127;
        int t = r2 >> 5, w = r2 & 31;
        B[(u * 4 + t) * 96 + h * 32 + w] = scW[i];
    }
    for (int i = tid; i < 2048; i += 256) {
        int nl = i >> 5, u = i & 31;
        int n = nodeBase + nl;
        x0s[i] = (n < NN) ? x[(long)n * 288 + u] : 0.f;
    }
    for (int i = tid; i < 256; i += 256) {
        int nl = i >> 2, t = i & 3;
        int n = nodeBase + nl;
        nas[i] = (n < NN) ? na[n * 4 + t] : 0.f;
    }
    __syncthreads();

    const int g = tid >> 5, c = tid & 31;
    float nav[8][4];
    #pragma unroll
    for (int j = 0; j < 8; ++j)
        #pragma unroll
        for (int t = 0; t < 4; ++t) nav[j][t] = nas[(g * 8 + j) * 4 + t];

    float acc[3][8];
    #pragma unroll
    for (int cc = 0; cc < 3; ++cc)
        #pragma unroll
        for (int j = 0; j < 8; ++j) acc[cc][j] = 0.f;

    for (int u = 0; u < 32; ++u) {
        float aj[8];
        #pragma unroll
        for (int j = 0; j < 8; ++j) aj[j] = x0s[(g * 8 + j) * 32 + u];  // broadcast
        #pragma unroll
        for (int t = 0; t < 4; ++t) {
            float b0 = B[(u * 4 + t) * 96 + c];
            float b1 = B[(u * 4 + t) * 96 + 32 + c];
            float b2 = B[(u * 4 + t) * 96 + 64 + c];
            #pragma unroll
            for (int j = 0; j < 8; ++j) {
                float p = aj[j] * nav[j][t];
                acc[0][j] += p * b0;
                acc[1][j] += p * b1;
                acc[2][j] += p * b2;
            }
        }
    }

    const float inv_sc = 0.08838834764831845f;  // 1/sqrt(128)
    #pragma unroll
    for (int j = 0; j < 8; ++j) {
        int n = nodeBase + g * 8 + j;
        if (n < NN) {
            #pragma unroll
            for (int cc = 0; cc < 3; ++cc)
                sc[((long)cc * NN + n) * 32 + c] = acc[cc][j] * inv_sc;
        }
    }
}

// ---------------------------------------------------------------------------
// CSR build: histogram -> exclusive scan -> stable-ish scatter of edge ids.
// ---------------------------------------------------------------------------
__global__ __launch_bounds__(256) void hist_kernel(
    const int* __restrict__ ei, int* __restrict__ counts)
{
    int e = blockIdx.x * 256 + threadIdx.x;
    if (e < NE) atomicAdd(&counts[ei[NE + e]], 1);
}

__global__ __launch_bounds__(1024) void scan_kernel(
    const int* __restrict__ counts, int* __restrict__ offsets)
{
    __shared__ int partial[1024];
    const int t = threadIdx.x;
    const int base = t * 20;          // 1024*20 = 20480 >= NN
    int loc[20];
    int s = 0;
    #pragma unroll
    for (int i = 0; i < 20; ++i) {
        int v = (base + i < NN) ? counts[base + i] : 0;
        loc[i] = s;
        s += v;
    }
    partial[t] = s;
    __syncthreads();
    for (int off = 1; off < 1024; off <<= 1) {
        int v = (t >= off) ? partial[t - off] : 0;
        __syncthreads();
        partial[t] += v;
        __syncthreads();
    }
    int pre = (t == 0) ? 0 : partial[t - 1];
    #pragma unroll
    for (int i = 0; i < 20; ++i)
        if (base + i <= NN) offsets[base + i] = pre + loc[i];
}

__global__ __launch_bounds__(256) void scatter_ids(
    const int* __restrict__ ei, const int* __restrict__ offsets,
    int* __restrict__ cursor, int* __restrict__ sidx)
{
    int e = blockIdx.x * 256 + threadIdx.x;
    if (e < NE) {
        int d = ei[NE + e];
        int pos = offsets[d] + atomicAdd(&cursor[d], 1);
        sidx[pos] = e;
    }
}

// ---------------------------------------------------------------------------
// Kernel B1: w = silu(ee@Wm0/sqrt8) @ Wm1 / sqrt64, computed in SORTED edge
// order for a chunk [jb, jb+ECH). wbuf row = chunk-local sorted position.
// ---------------------------------------------------------------------------
__global__ __launch_bounds__(256) void edge_w(
    const float* __restrict__ ee,
    const int*   __restrict__ sidx,
    const float* __restrict__ Wm0,
    const float* __restrict__ Wm1,
    float* __restrict__ w,
    int jb)
{
    __shared__ float wm0s[512];        // [k*64 + i]
    __shared__ float wm1t[96 * 68];    // [c*68 + k]
    __shared__ float ees[64 * 8];      // [e*8 + k]
    __shared__ float hs[64 * 68];      // [e*68 + k]
    const int tid = threadIdx.x;
    const int leb = blockIdx.x * 64;   // chunk-local sorted base

    for (int i = tid; i < 512; i += 256) wm0s[i] = Wm0[i];
    for (int i = tid; i < 6144; i += 256) {
        int k = i / 96, c = i % 96;
        wm1t[c * 68 + k] = Wm1[i];
    }
    for (int i = tid; i < 512; i += 256) {
        int le = i >> 3, k = i & 7;
        int e = sidx[jb + leb + le];
        ees[i] = ee[(long)e * 8 + k];
    }
    __syncthreads();

    // phase 1: h
    {
        const float inv_sqrt8 = 0.35355339059327373f;
        const int e = tid >> 2, i0 = (tid & 3) * 16;
        float emb[8];
        #pragma unroll
        for (int k = 0; k < 8; ++k) emb[k] = ees[e * 8 + k];
        #pragma unroll
        for (int i = 0; i < 16; ++i) {
            float t = 0.f;
            #pragma unroll
            for (int k = 0; k < 8; ++k) t += emb[k] * wm0s[k * 64 + i0 + i];
            hs[e * 68 + i0 + i] = silu_f(t * inv_sqrt8);
        }
    }
    __syncthreads();

    // phase 2: w rows
    const int u = tid & 31, g = tid >> 5;
    float acc[3][8];
    #pragma unroll
    for (int cc = 0; cc < 3; ++cc)
        #pragma unroll
        for (int j = 0; j < 8; ++j) acc[cc][j] = 0.f;

    #pragma unroll
    for (int k = 0; k < 64; k += 4) {
        float4 wv0 = *(const float4*)&wm1t[u * 68 + k];
        float4 wv1 = *(const float4*)&wm1t[(u + 32) * 68 + k];
        float4 wv2 = *(const float4*)&wm1t[(u + 64) * 68 + k];
        #pragma unroll
        for (int j = 0; j < 8; ++j) {
            float4 hv = *(const float4*)&hs[(g * 8 + j) * 68 + k];
            acc[0][j] += hv.x * wv0.x + hv.y * wv0.y + hv.z * wv0.z + hv.w * wv0.w;
            acc[1][j] += hv.x * wv1.x + hv.y * wv1.y + hv.z * wv1.z + hv.w * wv1.w;
            acc[2][j] += hv.x * wv2.x + hv.y * wv2.y + hv.z * wv2.z + hv.w * wv2.w;
        }
    }
    #pragma unroll
    for (int j = 0; j < 8; ++j) {
        long row = (long)(leb + g * 8 + j) * 96;
        #pragma unroll
        for (int cc = 0; cc < 3; ++cc)
            w[row + cc * 32 + u] = acc[cc][j] * 0.125f;   // fold 1/sqrt(HID)
    }
}

// ---------------------------------------------------------------------------
// Kernel B2: atomic-free gather-reduce. Group (32 lanes) owns node n; loops
// over the node's sorted-edge range intersected with this chunk. w rows are
// contiguous in sorted order -> streaming reads. Accumulate in registers,
// one read-modify-write of mid per node per chunk.
// ---------------------------------------------------------------------------
__global__ __launch_bounds__(256) void gather_reduce(
    const float* __restrict__ w,
    const float* __restrict__ ea,
    const int*   __restrict__ ei,
    const float* __restrict__ yAll,
    const int*   __restrict__ sidx,
    const int*   __restrict__ offsets,
    float* __restrict__ mid,
    int jb, int first)
{
    const int tid = threadIdx.x;
    const int n = blockIdx.x * 8 + (tid >> 5);
    const int u = tid & 31;
    if (n >= NN) return;

    const int j0 = offsets[n], j1 = offsets[n + 1];
    int lo = j0 > jb ? j0 : jb;
    int hi = j1 < jb + ECH ? j1 : jb + ECH;

    if (lo >= hi && !first) return;

    const float invAVG    = 0.17677669529663687f;  // 1/sqrt(32)
    const float c1        = 0.5773502691896258f * 0.17677669529663687f;  // /sqrt3/sqrt32
    const float c2        = 0.4472135954999579f * 0.17677669529663687f;  // /sqrt5/sqrt32

    float acc0 = 0.f, acc1 = 0.f, acc2 = 0.f;
    #pragma unroll 2
    for (int j = lo; j < hi; ++j) {
        const int e = sidx[j];                 // broadcast
        const int s = ei[e];                   // broadcast
        const float* wr  = w + (long)(j - jb) * 96;
        const float* eav = ea + (long)e * 9;
        const float* yb  = yAll + (long)s * 288;

        acc0 += wr[u] * yb[u] * eav[0];

        float d1 = yb[32 + u * 3 + 0] * eav[1]
                 + yb[32 + u * 3 + 1] * eav[2]
                 + yb[32 + u * 3 + 2] * eav[3];
        acc1 += wr[32 + u] * d1;

        float d2 = yb[128 + u * 5 + 0] * eav[4]
                 + yb[128 + u * 5 + 1] * eav[5]
                 + yb[128 + u * 5 + 2] * eav[6]
                 + yb[128 + u * 5 + 3] * eav[7]
                 + yb[128 + u * 5 + 4] * eav[8];
        acc2 += wr[64 + u] * d2;
    }
    acc0 *= invAVG; acc1 *= c1; acc2 *= c2;

    float* midRow = mid + (long)n * 96;
    if (first) {
        midRow[u]      = acc0;
        midRow[32 + u] = acc1;
        midRow[64 + u] = acc2;
    } else {
        midRow[u]      += acc0;
        midRow[32 + u] += acc1;
        midRow[64 + u] += acc2;
    }
}

// ---------------------------------------------------------------------------
// Kernel C: output GEMV + sc + silu.
// ---------------------------------------------------------------------------
__global__ __launch_bounds__(256) void node_out(
    const float* __restrict__ mid,
    const float* __restrict__ sc,
    const float* __restrict__ L0,
    const float* __restrict__ L1,
    const float* __restrict__ L2,
    float* __restrict__ out)
{
    __shared__ float l0[32 * 32];
    __shared__ float l1[64 * 32];
    __shared__ float l2[96 * 32];
    __shared__ float ms[8][96];
    const int tid = threadIdx.x;
    const int nodeBase = blockIdx.x * 8;

    for (int i = tid; i < 1024; i += 256) l0[i] = L0[i];
    for (int i = tid; i < 2048; i += 256) l1[i] = L1[i];
    for (int i = tid; i < 3072; i += 256) l2[i] = L2[i];
    for (int i = tid; i < 768; i += 256) {
        int nl = i / 96, c = i % 96;
        int n = nodeBase + nl;
        ms[nl][c] = (n < NN) ? mid[(long)n * 96 + c] : 0.f;
    }
    __syncthreads();

    const int nl = tid >> 5, wv = tid & 31;
    const int n = nodeBase + nl;
    if (n >= NN) return;

    float a0 = 0.f, a1 = 0.f, a2 = 0.f;
    #pragma unroll
    for (int u = 0; u < 32; ++u) {
        float m = ms[nl][u];
        a0 += m * l0[u * 32 + wv];
        a1 += m * l1[u * 32 + wv];
        a2 += m * l2[u * 32 + wv];
    }
    #pragma unroll
    for (int u = 32; u < 64; ++u) {
        float m = ms[nl][u];
        a1 += m * l1[u * 32 + wv];
        a2 += m * l2[u * 32 + wv];
    }
    #pragma unroll
    for (int u = 64; u < 96; ++u) a2 += ms[nl][u] * l2[u * 32 + wv];

    const float is32 = 0.17677669529663687f;
    const float is64 = 0.125f;
    const float is96 = 0.10206207261596575f;
    const long base = (long)n * 32 + wv;
    out[base]                     = silu_f(a0 * is32 + sc[base]);
    out[(long)NN * 32 + base]     = silu_f(a1 * is64 + sc[(long)NN * 32 + base]);
    out[(long)2 * NN * 32 + base] = silu_f(a2 * is96 + sc[(long)2 * NN * 32 + base]);
}

extern "C" void kernel_launch(void* const* d_in, const int* in_sizes, int n_in,
                              void* d_out, int out_size, void* d_ws, size_t ws_size,
                              hipStream_t stream)
{
    const float* x   = (const float*)d_in[0];
    const float* na  = (const float*)d_in[1];
    const float* ee  = (const float*)d_in[2];
    const float* ea  = (const float*)d_in[3];
    const int*   ei  = (const int*)d_in[4];
    const float* W10 = (const float*)d_in[5];
    const float* W11 = (const float*)d_in[6];
    const float* W12 = (const float*)d_in[7];
    const float* Wm0 = (const float*)d_in[8];
    const float* Wm1 = (const float*)d_in[9];
    const float* L0  = (const float*)d_in[10];
    const float* L1  = (const float*)d_in[11];
    const float* L2  = (const float*)d_in[12];
    const float* scW = (const float*)d_in[13];
    float* out = (float*)d_out;

    float* yAll    = (float*)d_ws;                  // NN*288
    float* sc      = yAll + (size_t)NN * 288;       // 3*NN*32
    float* mid     = sc + (size_t)3 * NN * 32;      // NN*96
    int*   counts  = (int*)(mid + (size_t)NN * 96); // NN
    int*   offsets = counts + NN;                   // NN+1
    int*   cursor  = offsets + NN + 1;              // NN
    int*   sidx    = cursor + NN;                   // NE
    float* wbuf    = (float*)(sidx + NE);           // ECH*96

    hipMemsetAsync(counts, 0, NN * sizeof(int), stream);
    hipMemsetAsync(cursor, 0, NN * sizeof(int), stream);

    node_y<<<(NN + 7) / 8, 256, 0, stream>>>(x, W10, W11, W12, yAll);
    node_sc<<<(NN + 63) / 64, 256, 0, stream>>>(x, na, scW, sc);

    hist_kernel<<<(NE + 255) / 256, 256, 0, stream>>>(ei, counts);
    scan_kernel<<<1, 1024, 0, stream>>>(counts, offsets);
    scatter_ids<<<(NE + 255) / 256, 256, 0, stream>>>(ei, offsets, cursor, sidx);

    for (int c = 0; c < NE / ECH; ++c) {
        int jb = c * ECH;
        edge_w<<<ECH / 64, 256, 0, stream>>>(ee, sidx, Wm0, Wm1, wbuf, jb);
        gather_reduce<<<(NN + 7) / 8, 256, 0, stream>>>(wbuf, ea, ei, yAll, sidx,
                                                        offsets, mid, jb, c == 0);
    }

    node_out<<<(NN + 7) / 8, 256, 0, stream>>>(mid, sc, L0, L1, L2, out);
}